// Round 2
// 249.264 us; speedup vs baseline: 1.0029x; 1.0029x over previous
//
#include <hip/hip_runtime.h>
#include <stdint.h>

#define Bz 2
#define Sz 2048
#define Dz 1024
#define Hz 16
#define HDz 64
#define Mz (Bz*Sz)   // 4096

typedef unsigned short u16;
typedef __attribute__((ext_vector_type(8))) __bf16 bf16x8;
typedef __attribute__((ext_vector_type(4))) __bf16 bf16x4;
typedef __attribute__((ext_vector_type(8))) unsigned short u16x8;
typedef __attribute__((ext_vector_type(4))) float f32x4;

#define C1 0.1803368801111243f   /* 0.125 * log2(e) */

__device__ __forceinline__ u16 f2bf(float f) {
  union { float f; unsigned u; } v; v.f = f;
  unsigned r = v.u + 0x7fffu + ((v.u >> 16) & 1u);
  return (u16)(r >> 16);
}

__device__ __forceinline__ void async16(void* lds, const void* g) {
  __builtin_amdgcn_global_load_lds(
      (const __attribute__((address_space(1))) unsigned int*)g,
      (__attribute__((address_space(3))) unsigned int*)lds, 16, 0, 0);
}

// ------------- fp32 -> bf16 for q/k/v in one launch (grid.y selects) -------------
__global__ void cvt3_kernel(const float* __restrict__ q, const float* __restrict__ k,
                            const float* __restrict__ v,
                            u16* __restrict__ xq, u16* __restrict__ xk, u16* __restrict__ xv,
                            int n4) {
  const float* in = blockIdx.y == 0 ? q : blockIdx.y == 1 ? k : v;
  u16* out = blockIdx.y == 0 ? xq : blockIdx.y == 1 ? xk : xv;
  int i = blockIdx.x * blockDim.x + threadIdx.x;
  if (i < n4) {
    float4 t = ((const float4*)in)[i];
    ((ushort4*)out)[i] = make_ushort4(f2bf(t.x), f2bf(t.y), f2bf(t.z), f2bf(t.w));
  }
}

// ------- W[K][N] fp32 -> Wt[N][K] bf16 (transpose+convert), grid.z selects matrix -------
__global__ void wt_cvt_kernel(const float* __restrict__ w0, const float* __restrict__ w1,
                              const float* __restrict__ w2, const float* __restrict__ w3,
                              u16* __restrict__ Wt /* 4 stacked [N][K] */) {
  const float* W = blockIdx.z == 0 ? w0 : blockIdx.z == 1 ? w1 : blockIdx.z == 2 ? w2 : w3;
  u16* o = Wt + (size_t)blockIdx.z * Dz * Dz;
  __shared__ __align__(16) float t[32][33];
  int n0 = blockIdx.x * 32, k0 = blockIdx.y * 32;
  int x = threadIdx.x, y = threadIdx.y;   // block (32,8)
#pragma unroll
  for (int i = 0; i < 4; ++i)
    t[y + i*8][x] = W[(size_t)(k0 + y + i*8) * Dz + n0 + x];
  __syncthreads();
#pragma unroll
  for (int i = 0; i < 4; ++i)
    o[(size_t)(n0 + y + i*8) * Dz + k0 + x] = f2bf(t[x][y + i*8]);
}

// ---- Vp[B*S][D] bf16 -> Vt[B][H][HD][S] bf16 (per-head transpose) ----
__global__ void __launch_bounds__(256)
vtrans_kernel(const u16* __restrict__ Vp, u16* __restrict__ Vt) {
  __shared__ __align__(16) u16 t[64][72];
  int s0 = blockIdx.x * 64, bh = blockIdx.y;
  int b = bh >> 4;
  int h = bh & 15;
  int tid = threadIdx.x;
#pragma unroll
  for (int p = 0; p < 4; ++p) {
    int c = p * 256 + tid;
    int row = c >> 4, off = (c & 15) * 4;
    ushort4 v = *(const ushort4*)(Vp + (size_t)(b * Sz + s0 + row) * Dz + h * 64 + off);
    *(ushort4*)&t[row][off] = v;
  }
  __syncthreads();
#pragma unroll
  for (int p = 0; p < 4; ++p) {
    int c = p * 256 + tid;
    int d = c >> 4, sc = (c & 15) * 4;
    ushort4 v = make_ushort4(t[sc + 0][d], t[sc + 1][d], t[sc + 2][d], t[sc + 3][d]);
    *(ushort4*)(Vt + (size_t)(bh * 64 + d) * Sz + s0 + sc) = v;
  }
}

// -------- fused QKV GEMM: 128x128 tile; blockIdx.x>>3 selects {Q,K,V} --------
__global__ void __launch_bounds__(256)
gemm_qkv(const u16* __restrict__ xq, const u16* __restrict__ xk, const u16* __restrict__ xv,
         const u16* __restrict__ Wt3,
         const float* __restrict__ bq, const float* __restrict__ bk, const float* __restrict__ bv,
         u16* __restrict__ Qp, u16* __restrict__ Kp, u16* __restrict__ Vp)
{
  __shared__ __align__(16) u16 lA[128][32];
  __shared__ __align__(16) u16 lB[128][32];
  const int sel = blockIdx.x >> 3;
  const int n0 = (blockIdx.x & 7) * 128;
  const int m0 = blockIdx.y * 128;
  const u16* A = sel == 0 ? xq : sel == 1 ? xk : xv;
  const u16* Bt = Wt3 + (size_t)sel * Dz * Dz;
  const float* bias = sel == 0 ? bq : sel == 1 ? bk : bv;
  u16* Cv = sel == 0 ? Qp : sel == 1 ? Kp : Vp;

  const int tid = threadIdx.x;
  const int w = tid >> 6, lane = tid & 63;
  const int wm = (w >> 1) * 64, wn = (w & 1) * 64;
  const int l16 = lane & 15, qd = lane >> 4;

  f32x4 acc[4][4];
#pragma unroll
  for (int i = 0; i < 4; ++i)
#pragma unroll
    for (int j = 0; j < 4; ++j) acc[i][j] = (f32x4){0.f, 0.f, 0.f, 0.f};

  const int r0 = tid >> 2, c0 = (tid & 3) * 8;
  const int r1 = r0 + 64;

  for (int k0 = 0; k0 < Dz; k0 += 32) {
    __syncthreads();
    async16(&lA[r0][c0], A  + (size_t)(m0 + r0) * Dz + k0 + c0);
    async16(&lB[r0][c0], Bt + (size_t)(n0 + r0) * Dz + k0 + c0);
    async16(&lA[r1][c0], A  + (size_t)(m0 + r1) * Dz + k0 + c0);
    async16(&lB[r1][c0], Bt + (size_t)(n0 + r1) * Dz + k0 + c0);
    __syncthreads();
    bf16x8 af[4], bfv[4];
#pragma unroll
    for (int t = 0; t < 4; ++t) {
      af[t]  = *(const bf16x8*)&lA[wm + t * 16 + l16][qd * 8];
      bfv[t] = *(const bf16x8*)&lB[wn + t * 16 + l16][qd * 8];
    }
#pragma unroll
    for (int mt = 0; mt < 4; ++mt)
#pragma unroll
      for (int nt = 0; nt < 4; ++nt)
        acc[mt][nt] = __builtin_amdgcn_mfma_f32_16x16x32_bf16(af[mt], bfv[nt], acc[mt][nt], 0, 0, 0);
  }

#pragma unroll
  for (int nt = 0; nt < 4; ++nt) {
    const int n = n0 + wn + nt * 16 + l16;
    const float bvl = bias[n];
#pragma unroll
    for (int mt = 0; mt < 4; ++mt)
#pragma unroll
      for (int r = 0; r < 4; ++r) {
        const int m = m0 + wm + mt * 16 + qd * 4 + r;
        Cv[(size_t)m * Dz + n] = f2bf(acc[mt][nt][r] + bvl);
      }
  }
}

// -------- FC GEMM: 128(M)x64(N) tile for 2 blocks/CU at N=1024, fp32 out --------
__global__ void __launch_bounds__(256)
gemm_fc(const u16* __restrict__ A, const u16* __restrict__ Bt,
        const float* __restrict__ bias, float* __restrict__ C)
{
  __shared__ __align__(16) u16 lA[128][32];
  __shared__ __align__(16) u16 lB[64][32];
  const int m0 = blockIdx.y * 128, n0 = blockIdx.x * 64;
  const int tid = threadIdx.x;
  const int w = tid >> 6, lane = tid & 63;
  const int wm = (w >> 1) * 64, wn = (w & 1) * 32;
  const int l16 = lane & 15, qd = lane >> 4;

  f32x4 acc[4][2];
#pragma unroll
  for (int i = 0; i < 4; ++i)
#pragma unroll
    for (int j = 0; j < 2; ++j) acc[i][j] = (f32x4){0.f, 0.f, 0.f, 0.f};

  const int r0 = tid >> 2, c0 = (tid & 3) * 8;

  for (int k0 = 0; k0 < Dz; k0 += 32) {
    __syncthreads();
    async16(&lA[r0][c0],      A  + (size_t)(m0 + r0) * Dz + k0 + c0);
    async16(&lA[r0 + 64][c0], A  + (size_t)(m0 + r0 + 64) * Dz + k0 + c0);
    async16(&lB[r0][c0],      Bt + (size_t)(n0 + r0) * Dz + k0 + c0);
    __syncthreads();
    bf16x8 af[4], bfv[2];
#pragma unroll
    for (int t = 0; t < 4; ++t)
      af[t] = *(const bf16x8*)&lA[wm + t * 16 + l16][qd * 8];
#pragma unroll
    for (int t = 0; t < 2; ++t)
      bfv[t] = *(const bf16x8*)&lB[wn + t * 16 + l16][qd * 8];
#pragma unroll
    for (int mt = 0; mt < 4; ++mt)
#pragma unroll
      for (int nt = 0; nt < 2; ++nt)
        acc[mt][nt] = __builtin_amdgcn_mfma_f32_16x16x32_bf16(af[mt], bfv[nt], acc[mt][nt], 0, 0, 0);
  }

#pragma unroll
  for (int nt = 0; nt < 2; ++nt) {
    const int n = n0 + wn + nt * 16 + l16;
    const float bvl = bias[n];
#pragma unroll
    for (int mt = 0; mt < 4; ++mt)
#pragma unroll
      for (int r = 0; r < 4; ++r) {
        const int m = m0 + wm + mt * 16 + qd * 4 + r;
        C[(size_t)m * Dz + n] = acc[mt][nt][r] + bvl;
      }
  }
}

// ---------------- fused flash-style attention (shift-0 softmax) ----------------
// grid (S/128, B*H), block 256 (4 waves; wave w owns q-rows [w*32, w*32+32)).
// Swapped QK^T: st = mfma(K_frag, Q_frag) gives lane (l16,qd): q-row = l16 (within
// 16-strip mt), s = nt*16 + qd*4 + r — contiguous in s. So the P write to LDS is a
// single 8-byte ds_write_b64 per (mt,nt) instead of 64 scalar ds_write_b16 scatters.
// lP memory layout [q][s] is IDENTICAL to the proven kernel, so the PV read path,
// ones-rowsum MFMA, and epilogue are unchanged.
__global__ void __launch_bounds__(256, 2)
attn_kernel(const u16* __restrict__ Qp, const u16* __restrict__ Kp,
            const u16* __restrict__ Vt, u16* __restrict__ Ao)
{
  __shared__ __align__(16) u16 lK[128][72];     // stride 144 B (≡16 mod 128)
  __shared__ __align__(16) u16 lV[64][136];     // stride 272 B
  __shared__ __align__(16) u16 lP[4][32][136];  // per-wave P

  const int q0 = blockIdx.x * 128;
  const int bh = blockIdx.y;
  const int b = bh >> 4, h = bh & 15;
  const int tid = threadIdx.x, w = tid >> 6, lane = tid & 63;
  const int l16 = lane & 15, qd = lane >> 4;

  const int krow = tid >> 3, kcol = (tid & 7) * 8;    // + p*32 rows
  const int vrow = tid >> 4, vcol = (tid & 15) * 8;   // + p*16 rows

  // prefetch tile 0 into registers
  u16x8 kreg[4], vreg[4];
#pragma unroll
  for (int p = 0; p < 4; ++p) {
    kreg[p] = *(const u16x8*)(Kp + (size_t)(b * Sz + p * 32 + krow) * Dz + h * 64 + kcol);
    vreg[p] = *(const u16x8*)(Vt + (size_t)(bh * 64 + p * 16 + vrow) * Sz + vcol);
  }

  // Q fragments in registers, reused for all kv tiles
  bf16x8 qf[2][2];
#pragma unroll
  for (int mt = 0; mt < 2; ++mt)
#pragma unroll
    for (int ks = 0; ks < 2; ++ks)
      qf[mt][ks] = *(const bf16x8*)(Qp + (size_t)(b * Sz + q0 + w * 32 + mt * 16 + l16) * Dz
                                    + h * 64 + ks * 32 + qd * 8);

  // ones B-fragment (bf16 1.0)
  u16x8 ob;
#pragma unroll
  for (int i = 0; i < 8; ++i) ob[i] = 0x3F80u;
  const bf16x8 onesf = __builtin_bit_cast(bf16x8, ob);

  f32x4 oacc[2][4], lacc[2];
#pragma unroll
  for (int i = 0; i < 2; ++i) {
    lacc[i] = (f32x4){0.f, 0.f, 0.f, 0.f};
#pragma unroll
    for (int j = 0; j < 4; ++j) oacc[i][j] = (f32x4){0.f, 0.f, 0.f, 0.f};
  }

  for (int t = 0; t < Sz / 128; ++t) {
    __syncthreads();
#pragma unroll
    for (int p = 0; p < 4; ++p) {
      *(u16x8*)&lK[p * 32 + krow][kcol] = kreg[p];
      *(u16x8*)&lV[p * 16 + vrow][vcol] = vreg[p];
    }
    if (t + 1 < Sz / 128) {
      const int kv = (t + 1) * 128;
#pragma unroll
      for (int p = 0; p < 4; ++p) {
        kreg[p] = *(const u16x8*)(Kp + (size_t)(b * Sz + kv + p * 32 + krow) * Dz + h * 64 + kcol);
        vreg[p] = *(const u16x8*)(Vt + (size_t)(bh * 64 + p * 16 + vrow) * Sz + kv + vcol);
      }
    }
    __syncthreads();

    // S^T = K @ Q^T per 16-s strip; P = exp2(s*C1) -> bf16 -> one b64 store each
#pragma unroll
    for (int nt = 0; nt < 8; ++nt) {
      const bf16x8 kf0 = *(const bf16x8*)&lK[nt * 16 + l16][qd * 8];
      const bf16x8 kf1 = *(const bf16x8*)&lK[nt * 16 + l16][32 + qd * 8];
#pragma unroll
      for (int mt = 0; mt < 2; ++mt) {
        f32x4 st = (f32x4){0.f, 0.f, 0.f, 0.f};
        st = __builtin_amdgcn_mfma_f32_16x16x32_bf16(kf0, qf[mt][0], st, 0, 0, 0);
        st = __builtin_amdgcn_mfma_f32_16x16x32_bf16(kf1, qf[mt][1], st, 0, 0, 0);
        bf16x4 pv;
        pv[0] = (__bf16)exp2f(st[0] * C1);
        pv[1] = (__bf16)exp2f(st[1] * C1);
        pv[2] = (__bf16)exp2f(st[2] * C1);
        pv[3] = (__bf16)exp2f(st[3] * C1);
        *(bf16x4*)&lP[w][mt * 16 + l16][nt * 16 + qd * 4] = pv;
      }
    }

    // O += P @ V ;  l += P @ 1   (intra-wave, no barrier)
#pragma unroll
    for (int ks = 0; ks < 4; ++ks) {
      bf16x8 pa[2], vb[4];
      pa[0] = *(const bf16x8*)&lP[w][l16     ][ks * 32 + qd * 8];
      pa[1] = *(const bf16x8*)&lP[w][16 + l16][ks * 32 + qd * 8];
#pragma unroll
      for (int nt = 0; nt < 4; ++nt)
        vb[nt] = *(const bf16x8*)&lV[nt * 16 + l16][ks * 32 + qd * 8];
#pragma unroll
      for (int mt = 0; mt < 2; ++mt) {
#pragma unroll
        for (int nt = 0; nt < 4; ++nt)
          oacc[mt][nt] = __builtin_amdgcn_mfma_f32_16x16x32_bf16(pa[mt], vb[nt], oacc[mt][nt], 0, 0, 0);
        lacc[mt] = __builtin_amdgcn_mfma_f32_16x16x32_bf16(pa[mt], onesf, lacc[mt], 0, 0, 0);
      }
    }
  }

  // normalize + store
#pragma unroll
  for (int mt = 0; mt < 2; ++mt)
#pragma unroll
    for (int r = 0; r < 4; ++r) {
      const float inv = 1.0f / lacc[mt][r];
      const int row = q0 + w * 32 + mt * 16 + qd * 4 + r;
#pragma unroll
      for (int nt = 0; nt < 4; ++nt) {
        const int col = h * 64 + nt * 16 + l16;
        Ao[(size_t)(b * Sz + row) * Dz + col] = f2bf(oacc[mt][nt][r] * inv);
      }
    }
}

// ---------------- host launch ----------------
extern "C" void kernel_launch(void* const* d_in, const int* in_sizes, int n_in,
                              void* d_out, int out_size, void* d_ws, size_t ws_size,
                              hipStream_t stream) {
  const float* query = (const float*)d_in[0];
  const float* key   = (const float*)d_in[1];
  const float* value = (const float*)d_in[2];
  const float* w_q  = (const float*)d_in[3];
  const float* b_q  = (const float*)d_in[4];
  const float* w_k  = (const float*)d_in[5];
  const float* b_k  = (const float*)d_in[6];
  const float* w_v  = (const float*)d_in[7];
  const float* b_v  = (const float*)d_in[8];
  const float* w_fc = (const float*)d_in[9];
  const float* b_fc = (const float*)d_in[10];
  float* out = (float*)d_out;

  const size_t XE = (size_t)Mz * Dz;   // 4 Mi elements
  const size_t WE = (size_t)Dz * Dz;   // 1 Mi elements
  u16* Xq  = (u16*)d_ws;               // bf16 inputs
  u16* Xk  = Xq + XE;
  u16* Xv  = Xk + XE;
  u16* Wt  = Xv + XE;                  // 4 stacked transposed weights [N][K]: q,k,v,fc
  u16* Wtf = Wt + 3 * WE;
  u16* Qp  = Wt + 4 * WE;              // projections
  u16* Kp  = Qp + XE;
  u16* Vp  = Kp + XE;
  u16* Vt  = Xk;                       // reuse: Xk dead after QKV projections
  u16* Ao  = Xq;                       // reuse: Xq dead after QKV projections

  const int n4 = (int)(XE / 4);
  cvt3_kernel<<<dim3(n4 / 256, 3), 256, 0, stream>>>(query, key, value, Xq, Xk, Xv, n4);

  wt_cvt_kernel<<<dim3(Dz / 32, Dz / 32, 4), dim3(32, 8), 0, stream>>>(w_q, w_k, w_v, w_fc, Wt);

  gemm_qkv<<<dim3(24, Mz / 128), 256, 0, stream>>>(Xq, Xk, Xv, Wt, b_q, b_k, b_v, Qp, Kp, Vp);

  vtrans_kernel<<<dim3(Sz / 64, Bz * Hz), 256, 0, stream>>>(Vp, Vt);

  attn_kernel<<<dim3(Sz / 128, Bz * Hz), 256, 0, stream>>>(Qp, Kp, Vt, Ao);

  gemm_fc<<<dim3(Dz / 64, Mz / 128), 256, 0, stream>>>(Ao, Wtf, b_fc, out);
}